// Round 7
// baseline (313.106 us; speedup 1.0000x reference)
//
#include <hip/hip_runtime.h>
#include <hip/hip_bf16.h>

#define BN_EPS 1e-5f

typedef short s8v __attribute__((ext_vector_type(8)));
typedef float f4v __attribute__((ext_vector_type(4)));
typedef unsigned short u16x8 __attribute__((ext_vector_type(8)));

__device__ __forceinline__ float bu2f(unsigned short u) {
    union { unsigned int i; float f; } c; c.i = ((unsigned int)u) << 16; return c.f;
}
__device__ __forceinline__ unsigned short f2bu(float f) {
    union { float f; unsigned int i; } c; c.f = f;
    unsigned int i = c.i;
    i += 0x7FFFu + ((i >> 16) & 1u);   // RNE
    return (unsigned short)(i >> 16);
}
__device__ __forceinline__ float gelu_exact(float x) {
    return 0.5f * x * (1.0f + erff(x * 0.70710678118654752f));
}
__device__ __forceinline__ float ldin(const void* p, long i, bool f32) {
    return f32 ? ((const float*)p)[i] : bu2f(((const unsigned short*)p)[i]);
}
__device__ __forceinline__ s8v ldfrag(const unsigned short* p) {
    return *reinterpret_cast<const s8v*>(p);
}
// async 16B global->LDS DMA (lane i lands at lds + i*16; lds must be wave-uniform)
__device__ __forceinline__ void gld16(const void* g, void* l) {
    __builtin_amdgcn_global_load_lds(
        (const __attribute__((address_space(1))) unsigned int*)g,
        (__attribute__((address_space(3))) unsigned int*)l, 16, 0, 0);
}
// swizzled fragment read from unpadded 32-short rows: slot = quad ^ ((row>>1)&3)
__device__ __forceinline__ s8v ldsw32(const unsigned short* T, int row, int quad) {
    return *reinterpret_cast<const s8v*>(T + row * 32 + ((quad ^ ((row >> 1) & 3)) << 3));
}
// swizzled read from unpadded 64-short rows (8 chunks): slot = chunk ^ (row&7)
__device__ __forceinline__ s8v ldsw64(const unsigned short* T, int row, int chunk) {
    return *reinterpret_cast<const s8v*>(T + row * 64 + ((chunk ^ (row & 7)) << 3));
}
__device__ __forceinline__ int detect_f32(const unsigned short* xu) {
    int insane = 0;
    for (int i = 0; i < 128; ++i) {
        unsigned int e = (xu[i] >> 7) & 0xFFu;
        if (e == 255u || (e != 0u && (e < 96u || e > 159u))) ++insane;
    }
    return (insane >= 16) ? 1 : 0;
}

// ------------- fused prep: dtype flag + weight conv + x transposes ----------
// blocks [0,960): weights (8 el/thread); [960,3008): xT; [3008,3520): xqT
__global__ __launch_bounds__(256)
void prep_kernel(const void* __restrict__ x,
                 const void* __restrict__ w0, const void* __restrict__ w1,
                 const void* __restrict__ w2, const void* __restrict__ w3,
                 const void* __restrict__ w4,
                 unsigned short* __restrict__ wdst,
                 unsigned short* __restrict__ xT,
                 unsigned short* __restrict__ xqT,
                 int* __restrict__ dtf)
{
    __shared__ int sflag;
    __shared__ unsigned short T[64][66];
    const int tid = threadIdx.x;
    const int bid = blockIdx.x;
    if (tid == 0) {
        int fl = detect_f32((const unsigned short*)x);
        sflag = fl;
        if (bid == 0) *dtf = fl;
    }
    __syncthreads();
    const bool f = (sflag != 0);

    if (bid < 960) {
        long idx = (long)bid * 2048 + tid * 8;
        const void* s; long off;
        if      (idx <  327680L) { s = w0; off = idx; }
        else if (idx <  393216L) { s = w1; off = idx - 327680L; }
        else if (idx <  917504L) { s = w2; off = idx - 393216L; }
        else if (idx < 1441792L) { s = w3; off = idx - 917504L; }
        else                     { s = w4; off = idx - 1441792L; }
        u16x8 pk;
        if (f) {
            float4 a = *((const float4*)((const float*)s + off));
            float4 b = *((const float4*)((const float*)s + off + 4));
            pk[0]=f2bu(a.x); pk[1]=f2bu(a.y); pk[2]=f2bu(a.z); pk[3]=f2bu(a.w);
            pk[4]=f2bu(b.x); pk[5]=f2bu(b.y); pk[6]=f2bu(b.z); pk[7]=f2bu(b.w);
        } else {
            pk = *((const u16x8*)((const unsigned short*)s + off));
        }
        *reinterpret_cast<u16x8*>(wdst + idx) = pk;
        return;
    }
    // transpose branches: src x [b][256][1024] -> dst [b][ND][256]
    int b, c0, n0, ND; bool SUBS;
    if (bid < 3008) { int t = bid - 960;  b = t >> 6; int r = t & 63;
                      c0 = (r >> 4) * 64; n0 = (r & 15) * 64; ND = 1024; SUBS = false; }
    else            { int t = bid - 3008; b = t >> 4; int r = t & 15;
                      c0 = (r >> 2) * 64; n0 = (r & 3) * 64;  ND = 256;  SUBS = true; }
    unsigned short* dst = SUBS ? xqT : xT;
    {
        int nn = tid & 63, cq = tid >> 6;
        int n = n0 + nn;
        int sc = SUBS ? ((n >> 4) * 64 + (n & 15) * 2) : n;
        long base = ((long)b * 256 + c0 + cq * 16) * 1024 + sc;
        #pragma unroll
        for (int i = 0; i < 16; ++i)
            T[nn][cq * 16 + i] = f2bu(ldin(x, base + (long)i * 1024, f));
    }
    __syncthreads();
    {
        int cc = tid & 63, nq = tid >> 6;
        #pragma unroll
        for (int i = 0; i < 16; ++i) {
            int nn = nq * 16 + i;
            dst[((long)b * ND + n0 + nn) * 256 + c0 + cc] = T[nn][cc];
        }
    }
}

// ---------------- MFMA GEMM: C = BN(W @ X), X given transposed --------------
// A [M][K] bf16, B [b][N][K] bf16. Tile BM x 128, BK=64, async LDS staging.
// DBUF=false: single-buffer {stage, barrier, compute, barrier} (best when the
//   block queue is deep / LDS headroom buys residency -- kv, q).
// DBUF=true: attn-proven 2-phase {stage(t+1); compute(t); barrier} with
//   double-buffered LDS. Use ONLY where the grid caps residency at <= what
//   the doubled LDS allows (round-4 lesson) -- tail GEMMs (2/CU grids).
// OUT_MODE 0: transposed bf16 out0[b][N][M]
// OUT_MODE 1: kv split (out0=kvK [b*8+h][1024 n][32], out1=kvV [b*8+h][128][N])
// OUT_MODE 2: normal external out0 [b'][M][256], b'=n>>8 (N-folded batch)
// OUT_MODE 3: head-split transposed out0 [b*8+h][N][32]  (q projection)
template<int OUT_MODE, bool DO_GELU, bool PRESCALE, int BM, bool DBUF>
__global__ __launch_bounds__(256)
void mfma_gemm(const unsigned short* __restrict__ A,
               const unsigned short* __restrict__ B,
               const void* __restrict__ gg, const void* __restrict__ bb,
               const void* __restrict__ mmu, const void* __restrict__ vv,
               void* __restrict__ out0, unsigned short* __restrict__ out1,
               int M, int K, int N, const int* __restrict__ dtflag)
{
    constexpr int NF = (BM == 128) ? 4 : 2;
    constexpr int ATILE = BM * 64;
    constexpr int BTILE = 128 * 64;
    constexpr int MP0 = BM + 8;  // OUT_MODE 0 epilogue tile stride ([n][m] rows)
    constexpr int MP1 = 136;     // OUT_MODE 1 epilogue tile stride ([m][n] rows)
    constexpr int LOOPSH = (DBUF ? 2 : 1) * (ATILE + BTILE);
    constexpr int TILESH = (OUT_MODE == 1) ? 128 * MP1 : ((OUT_MODE == 0) ? 128 * MP0 : 0);
    constexpr int SMS = (LOOPSH > TILESH) ? LOOPSH : TILESH;
    __shared__ __align__(16) unsigned short smem[SMS];
    __shared__ float sS[BM], sO[BM];
    unsigned short* As = smem;                       // As[DBUF?2:1][ATILE]
    unsigned short* Bs = smem + (DBUF ? 2 : 1) * ATILE;
    unsigned short* Tt = smem;   // epilogue tile aliases (dead after K-loop)

    const bool wf = (*dtflag != 0);
    const int tid = threadIdx.x;
    const int lane = tid & 63;
    const int wave = tid >> 6;
    const int quad = lane >> 4;
    const int l15  = lane & 15;
    const int wm2 = (BM == 128) ? (wave >> 1) * 64 : 0;
    const int wn2 = (BM == 128) ? (wave & 1) * 64 : wave * 32;
    const int b  = blockIdx.z;
    const int bm = blockIdx.y * BM;
    const int bn = blockIdx.x * 128;

    if (tid < BM) {
        int m = bm + tid;
        float g  = ldin(gg,  m, wf), be = ldin(bb,  m, wf);
        float mu = ldin(mmu, m, wf), va = ldin(vv,  m, wf);
        float s = g * rsqrtf(va + BN_EPS);
        float o = be - mu * s;
        if (PRESCALE) { s *= 0.17677669529663687f; o *= 0.17677669529663687f; }
        sS[tid] = s; sO[tid] = o;
    }

    const unsigned short* Bb = B + (long)b * N * K;

    f4v acc[4][NF];
    #pragma unroll
    for (int i = 0; i < 4; ++i)
        #pragma unroll
        for (int j = 0; j < NF; ++j) acc[i][j] = (f4v){0.f, 0.f, 0.f, 0.f};

    const int lr8 = lane >> 3;   // row within 8-row stage group
    const int lc8 = lane & 7;    // chunk slot 0..7

    // stage one BK=64 tile pair into buffer sel (addressing = proven r2 form)
    auto stageAB = [&](int k0, int sel) {
        #pragma unroll
        for (int j = 0; j < (BM == 128 ? 4 : 2); ++j) {
            int base = wave * (BM == 128 ? 32 : 16) + j * 8;
            int r = base + lr8;
            gld16(A + (long)(bm + r) * K + k0 + ((lc8 ^ (r & 7)) << 3),
                  As + sel * ATILE + base * 64);
        }
        #pragma unroll
        for (int j = 0; j < 4; ++j) {
            int base = wave * 32 + j * 8;
            int r = base + lr8;
            gld16(Bb + (long)(bn + r) * K + k0 + ((lc8 ^ (r & 7)) << 3),
                  Bs + sel * BTILE + base * 64);
        }
    };
    auto computeTile = [&](const unsigned short* Asc, const unsigned short* Bsc) {
        #pragma unroll
        for (int sk = 0; sk < 2; ++sk) {
            s8v af[4], bfr[NF];
            #pragma unroll
            for (int i = 0; i < 4; ++i)
                af[i]  = ldsw64(Asc, wm2 + i * 16 + l15, sk * 4 + quad);
            #pragma unroll
            for (int j = 0; j < NF; ++j)
                bfr[j] = ldsw64(Bsc, wn2 + j * 16 + l15, sk * 4 + quad);
            #pragma unroll
            for (int i = 0; i < 4; ++i)
                #pragma unroll
                for (int j = 0; j < NF; ++j)
                    acc[i][j] = __builtin_amdgcn_mfma_f32_16x16x32_bf16(
                        af[i], bfr[j], acc[i][j], 0, 0, 0);
        }
    };

    if constexpr (DBUF) {
        const int NT = K >> 6;
        stageAB(0, 0);
        __syncthreads();                 // drain stage(0)
        for (int t = 0; t < NT; ++t) {
            const int cur = t & 1;
            if (t + 1 < NT) stageAB((t + 1) << 6, cur ^ 1);  // prefetch first
            computeTile(As + cur * ATILE, Bs + cur * BTILE);
            __syncthreads();             // drains prefetch + protects buffers
        }
    } else {
        for (int k0 = 0; k0 < K; k0 += 64) {
            stageAB(k0, 0);
            __syncthreads();
            computeTile(As, Bs);
            __syncthreads();
        }
    }

    // ---------------- epilogue: BN(+GELU) then store ----------------
    #pragma unroll
    for (int i = 0; i < 4; ++i) {
        int m0l = wm2 + i * 16 + quad * 4;
        int m0  = bm + m0l;
        float s0 = sS[m0l + 0], o0 = sO[m0l + 0];
        float s1 = sS[m0l + 1], o1 = sO[m0l + 1];
        float s2 = sS[m0l + 2], o2 = sO[m0l + 2];
        float s3 = sS[m0l + 3], o3 = sO[m0l + 3];
        #pragma unroll
        for (int j = 0; j < NF; ++j) {
            int nl = wn2 + j * 16 + l15;
            int n = bn + nl;
            float v0 = acc[i][j][0] * s0 + o0;
            float v1 = acc[i][j][1] * s1 + o1;
            float v2 = acc[i][j][2] * s2 + o2;
            float v3 = acc[i][j][3] * s3 + o3;
            if (DO_GELU) {
                v0 = gelu_exact(v0); v1 = gelu_exact(v1);
                v2 = gelu_exact(v2); v3 = gelu_exact(v3);
            }
            if (OUT_MODE == 0) {
                // stage [n][m] tile; coalesced read-out below
                ushort4 pk; pk.x = f2bu(v0); pk.y = f2bu(v1);
                pk.z = f2bu(v2); pk.w = f2bu(v3);
                *reinterpret_cast<ushort4*>(&Tt[nl * MP0 + m0l]) = pk;
            } else if (OUT_MODE == 1) {
                int h = m0 / 160, seg = m0 - h * 160;
                if (seg < 32) {
                    ushort4 pk; pk.x = f2bu(v0); pk.y = f2bu(v1);
                    pk.z = f2bu(v2); pk.w = f2bu(v3);
                    *reinterpret_cast<ushort4*>(
                        (unsigned short*)out0 + ((long)(b * 8 + h) * 1024 + n) * 32 + seg) = pk;
                } else {
                    // stage V rows [m][n]; coalesced read-out below
                    Tt[(m0l + 0) * MP1 + nl] = f2bu(v0);
                    Tt[(m0l + 1) * MP1 + nl] = f2bu(v1);
                    Tt[(m0l + 2) * MP1 + nl] = f2bu(v2);
                    Tt[(m0l + 3) * MP1 + nl] = f2bu(v3);
                }
            } else if (OUT_MODE == 2) {
                int b2 = n >> 8, nl2 = n & 255;
                long ob = ((long)b2 * M + m0) * 256 + nl2;
                if (wf) {
                    ((float*)out0)[ob + 0L * 256] = v0;
                    ((float*)out0)[ob + 1L * 256] = v1;
                    ((float*)out0)[ob + 2L * 256] = v2;
                    ((float*)out0)[ob + 3L * 256] = v3;
                } else {
                    ((unsigned short*)out0)[ob + 0L * 256] = f2bu(v0);
                    ((unsigned short*)out0)[ob + 1L * 256] = f2bu(v1);
                    ((unsigned short*)out0)[ob + 2L * 256] = f2bu(v2);
                    ((unsigned short*)out0)[ob + 3L * 256] = f2bu(v3);
                }
            } else {  // OUT_MODE == 3
                int h = m0 >> 5;
                ushort4 pk; pk.x = f2bu(v0); pk.y = f2bu(v1);
                pk.z = f2bu(v2); pk.w = f2bu(v3);
                *reinterpret_cast<ushort4*>(
                    (unsigned short*)out0 + ((long)(b * 8 + h) * 256 + n) * 32 + (m0 & 31)) = pk;
            }
        }
    }

    if (OUT_MODE == 0) {
        __syncthreads();
        // write 128 n-rows of BM m each, ushort8 per lane (fully coalesced)
        constexpr int CPR = BM / 8;              // 16B-chunks per n-row
        long ob = ((long)b * N + bn) * M + bm;
        #pragma unroll
        for (int c = 0; c < BM / 16; ++c) {      // 128*CPR/256 iters
            int cc = c * 256 + tid;
            int n = cc / CPR, mc = (cc % CPR) << 3;
            *reinterpret_cast<u16x8*>((unsigned short*)out0 + ob + (long)n * M + mc) =
                *reinterpret_cast<const u16x8*>(&Tt[n * MP0 + mc]);
        }
    } else if (OUT_MODE == 1) {
        __syncthreads();
        // V rows of this tile: all local m except the (single, aligned) K window
        int h0 = (bm + 159) / 160;
        int ks = h0 * 160;                      // K window [ks, ks+32) if in tile
        bool hasK = (ks < bm + 128);
        int kl = hasK ? (ks - bm) : 128;        // local K window start
        int nrows = hasK ? 96 : 128;
        for (int c = tid; c < nrows * 16; c += 256) {
            int row = c >> 4, ch = (c & 15) << 3;
            int ml = (row < kl) ? row : (row + 32);
            int m = bm + ml;
            int hh = m / 160, seg = m - hh * 160;
            *reinterpret_cast<u16x8*>(out1 +
                (((long)(b * 8 + hh) * 128) + (seg - 32)) * (long)N + bn + ch) =
                *reinterpret_cast<const u16x8*>(&Tt[ml * MP1 + ch]);
        }
    }
}

// ------- MFMA flash attention + GELU, static-max softmax, deferred sum ------
// Scores are BN-normalized (std ~0.5, max ~3): exp(min(s,30)) never overflows,
// so no online max, no alpha rescale, no per-tile reductions.
// K-loop: double-buffered K/V tiles, stage(t+1) issued BEFORE compute(t),
// single __syncthreads per tile (T3 minimum-2-phase; overlap = full compute).
// kvK [b*8+h][1024 n][32 d], kvV [b*8+h][128 v][1024 n],
// qh  [b*8+h][256 q][32 d] (pre-scaled), goT [b][256 q][1024 (h,v)]
__global__ __launch_bounds__(512, 4)
void attn_mfma(const unsigned short* __restrict__ kvK,
               const unsigned short* __restrict__ kvV,
               const unsigned short* __restrict__ qh,
               unsigned short* __restrict__ goT)
{
    __shared__ unsigned short Ks[2][64 * 32];   // 8 KB,  xor-swizzled
    __shared__ unsigned short Vs[2][128 * 64];  // 32 KB, xor-swizzled
    __shared__ unsigned short Ps[128][72];      // 18.4 KB
    __shared__ float redS[128];

    const int tid = threadIdx.x;
    const int lane = tid & 63;
    const int wave = tid >> 6;     // 0..7
    const int quad = lane >> 4;
    const int l15  = lane & 15;
    const int h    = blockIdx.x;   // 0..7
    const int b    = blockIdx.y;   // 0..31
    const int q0   = blockIdx.z * 128;   // q-half (z so siblings share XCD)
    const int wq   = wave * 16;          // block-local q base for this wave

    const unsigned short* Qb = qh  + (long)(b * 8 + h) * 256 * 32;
    const unsigned short* Kb = kvK + (long)(b * 8 + h) * 1024 * 32;
    const unsigned short* Vb = kvV + (long)(b * 8 + h) * 128 * 1024;

    s8v qf = ldfrag(Qb + (long)(q0 + wq + l15) * 32 + quad * 8);

    // hoisted per-lane global source pointers (tile t adds t*64 n-columns)
    const unsigned short* pK = Kb;
    if (wave < 4) {
        int r = wave * 16 + (lane >> 2);
        int c = (lane & 3) ^ ((r >> 1) & 3);
        pK = Kb + (long)r * 32 + (c << 3);
    }
    const int rb = wave * 16;
    const int r0 = rb + (lane >> 3), r1 = r0 + 8;
    const int sl = lane & 7;
    const unsigned short* pV0 = Vb + (long)r0 * 1024 + ((sl ^ (r0 & 7)) << 3);
    const unsigned short* pV1 = Vb + (long)r1 * 1024 + ((sl ^ (r1 & 7)) << 3);

    f4v o[8];
    #pragma unroll
    for (int i = 0; i < 8; ++i) o[i] = (f4v){0.f, 0.f, 0.f, 0.f};
    float rs[4] = {0.f, 0.f, 0.f, 0.f};   // deferred row-sum partials

    // prologue: stage tile 0 into buffer 0
    if (wave < 4) gld16(pK, &Ks[0][wave * 16 * 32]);
    gld16(pV0, &Vs[0][rb * 64]);
    gld16(pV1, &Vs[0][(rb + 8) * 64]);
    __syncthreads();               // drain stage(0)

    for (int t = 0; t < 16; ++t) {
        const int cur = t & 1;
        if (t < 15) {              // issue stage(t+1) BEFORE compute(t)
            const int nxt = cur ^ 1;
            const long adv = (long)(t + 1) * 64;
            if (wave < 4) gld16(pK + adv * 32, &Ks[nxt][wave * 16 * 32]);
            gld16(pV0 + adv, &Vs[nxt][rb * 64]);
            gld16(pV1 + adv, &Vs[nxt][(rb + 8) * 64]);
        }

        // S = Q K^T (16 q x 64 n per wave), then p = exp(s) straight away
        #pragma unroll
        for (int j = 0; j < 4; ++j) {
            s8v kf = ldsw32(&Ks[cur][0], j * 16 + l15, quad);
            f4v z = (f4v){0.f, 0.f, 0.f, 0.f};
            f4v sa = __builtin_amdgcn_mfma_f32_16x16x32_bf16(qf, kf, z, 0, 0, 0);
            #pragma unroll
            for (int r = 0; r < 4; ++r) {
                float p = __expf(fminf(sa[r], 30.f));
                rs[r] += p;
                Ps[wq + quad * 4 + r][j * 16 + l15] = f2bu(p);
            }
        }
        // wave-private P rows: LDS ops in-order per wave -> no barrier
        // O += V P^T
        #pragma unroll
        for (int ks = 0; ks < 2; ++ks) {
            s8v pf = ldfrag(&Ps[wq + l15][ks * 32 + quad * 8]);
            #pragma unroll
            for (int i = 0; i < 8; ++i) {
                s8v vf = ldsw64(&Vs[cur][0], i * 16 + l15, ks * 4 + quad);
                o[i] = __builtin_amdgcn_mfma_f32_16x16x32_bf16(vf, pf, o[i], 0, 0, 0);
            }
        }
        // single barrier per tile: drains stage(t+1) (vmcnt(0)) and orders
        // this tile's LDS reads before buffer[cur] is overwritten at t+1
        __syncthreads();
    }

    // single end-of-kernel row-sum reduction (16-lane groups)
    #pragma unroll
    for (int r = 0; r < 4; ++r) {
        float s = rs[r];
        s += __shfl_xor(s, 1);
        s += __shfl_xor(s, 2);
        s += __shfl_xor(s, 4);
        s += __shfl_xor(s, 8);
        if (l15 == 0) redS[wq + quad * 4 + r] = s;
    }
    float linv = 1.0f / redS[wq + l15];
    int q = q0 + wq + l15;
    #pragma unroll
    for (int i = 0; i < 8; ++i) {
        ushort4 pk;
        pk.x = f2bu(gelu_exact(o[i][0] * linv));
        pk.y = f2bu(gelu_exact(o[i][1] * linv));
        pk.z = f2bu(gelu_exact(o[i][2] * linv));
        pk.w = f2bu(gelu_exact(o[i][3] * linv));
        *reinterpret_cast<ushort4*>(
            goT + ((long)b * 256 + q) * 1024 + h * 128 + i * 16 + quad * 4) = pk;
    }
}

// ---------------------------------------------------------------------------
extern "C" void kernel_launch(void* const* d_in, const int* in_sizes, int n_in,
                              void* d_out, int out_size, void* d_ws, size_t ws_size,
                              hipStream_t stream)
{
    const void* x     = d_in[0];
    const void* kv_w  = d_in[1];
    const void* kv_g  = d_in[2];  const void* kv_b  = d_in[3];
    const void* kv_m  = d_in[4];  const void* kv_v  = d_in[5];
    const void* q_w   = d_in[6];
    const void* q_g   = d_in[7];  const void* q_b   = d_in[8];
    const void* q_m   = d_in[9];  const void* q_v   = d_in[10];
    const void* mg_w  = d_in[11];
    const void* mg_g  = d_in[12]; const void* mg_b  = d_in[13];
    const void* mg_m  = d_in[14]; const void* mg_v  = d_in[15];
    const void* fc1_w = d_in[16];
    const void* bn1_g = d_in[17]; const void* bn1_b = d_in[18];
    const void* bn1_m = d_in[19]; const void* bn1_v = d_in[20];
    const void* fc2_w = d_in[21];
    const void* bn2_g = d_in[22]; const void* bn2_b = d_in[23];
    const void* bn2_m = d_in[24]; const void* bn2_v = d_in[25];

    // ws layout (bf16 elements)
    unsigned short* ws  = (unsigned short*)d_ws;
    int*            dtf = (int*)d_ws;
    unsigned short* wsW  = ws + 8;               // 1,966,080
    unsigned short* wKV  = wsW;
    unsigned short* wQ   = wsW + 327680L;
    unsigned short* wMG  = wsW + 393216L;
    unsigned short* wFC1 = wsW + 917504L;
    unsigned short* wFC2 = wsW + 1441792L;
    unsigned short* xT   = ws + 1966088L;        // 8,388,608 (aliased by goT)
    unsigned short* goT  = xT;
    unsigned short* xqT  = ws + 10354696L;       // 2,097,152
    unsigned short* qhb  = ws + 12451848L;       // 2,097,152
    unsigned short* kvK  = ws + 14549000L;       // 8,388,608
    unsigned short* kvV  = ws + 22937608L;       // 33,554,432 (aliased by y1/y2)
    unsigned short* y1T  = kvV;                  // [8192][512]
    unsigned short* y2T  = kvV + 4194304L;       // [8192][1024]

    dim3 blk(256, 1, 1);

    // fused prep: dtype detect + weight conv + xT + xqT
    prep_kernel<<<3520, blk, 0, stream>>>(
        x, kv_w, q_w, mg_w, fc1_w, fc2_w, wsW, xT, xqT, dtf);

    // q proj + BN (scale folded) -> qh [b*8+h][256][32]
    mfma_gemm<3, false, true, 64, false><<<dim3(2, 4, 32), blk, 0, stream>>>(
        wQ, xqT, q_g, q_b, q_m, q_v, qhb, nullptr, 256, 256, 256, dtf);

    // kv proj + BN, split K [b*8+h][1024][32] / V [b*8+h][128][1024]
    // (single-buffer: deep block queue, LDS headroom buys residency)
    mfma_gemm<1, false, false, 128, false><<<dim3(8, 10, 32), blk, 0, stream>>>(
        wKV, xT, kv_g, kv_b, kv_m, kv_v, kvK, kvV, 1280, 256, 1024, dtf);

    // flash attention + GELU -> goT [b][256][1024]
    attn_mfma<<<dim3(8, 32, 2), dim3(512, 1, 1), 0, stream>>>(kvK, kvV, qhb, goT);

    // merge proj + BN -> y1T [8192][512]   (2-phase dbuf: grid-capped 2/CU)
    mfma_gemm<0, false, false, 64, true><<<dim3(64, 8, 1), blk, 0, stream>>>(
        wMG, goT, mg_g, mg_b, mg_m, mg_v, y1T, nullptr, 512, 1024, 8192, dtf);

    // fc1 + BN + GELU -> y2T [8192][1024]  (2-phase dbuf, 1024 blocks)
    mfma_gemm<0, true, false, 64, true><<<dim3(64, 16, 1), blk, 0, stream>>>(
        wFC1, y1T, bn1_g, bn1_b, bn1_m, bn1_v, y2T, nullptr, 1024, 512, 8192, dtf);

    // fc2 + BN -> d_out [b][512][16][16]   (2-phase dbuf)
    mfma_gemm<2, false, false, 64, true><<<dim3(64, 8, 1), blk, 0, stream>>>(
        wFC2, y2T, bn2_g, bn2_b, bn2_m, bn2_v, d_out, nullptr, 512, 1024, 8192, dtf);
}

// Round 8
// 293.988 us; speedup vs baseline: 1.0650x; 1.0650x over previous
//
#include <hip/hip_runtime.h>
#include <hip/hip_bf16.h>

#define BN_EPS 1e-5f

typedef short s8v __attribute__((ext_vector_type(8)));
typedef float f4v __attribute__((ext_vector_type(4)));
typedef unsigned short u16x8 __attribute__((ext_vector_type(8)));

__device__ __forceinline__ float bu2f(unsigned short u) {
    union { unsigned int i; float f; } c; c.i = ((unsigned int)u) << 16; return c.f;
}
__device__ __forceinline__ unsigned short f2bu(float f) {
    union { float f; unsigned int i; } c; c.f = f;
    unsigned int i = c.i;
    i += 0x7FFFu + ((i >> 16) & 1u);   // RNE
    return (unsigned short)(i >> 16);
}
__device__ __forceinline__ float gelu_exact(float x) {
    return 0.5f * x * (1.0f + erff(x * 0.70710678118654752f));
}
__device__ __forceinline__ float ldin(const void* p, long i, bool f32) {
    return f32 ? ((const float*)p)[i] : bu2f(((const unsigned short*)p)[i]);
}
__device__ __forceinline__ s8v ldfrag(const unsigned short* p) {
    return *reinterpret_cast<const s8v*>(p);
}
// async 16B global->LDS DMA (lane i lands at lds + i*16; lds must be wave-uniform)
__device__ __forceinline__ void gld16(const void* g, void* l) {
    __builtin_amdgcn_global_load_lds(
        (const __attribute__((address_space(1))) unsigned int*)g,
        (__attribute__((address_space(3))) unsigned int*)l, 16, 0, 0);
}
// swizzled fragment read from unpadded 32-short rows: slot = quad ^ ((row>>1)&3)
__device__ __forceinline__ s8v ldsw32(const unsigned short* T, int row, int quad) {
    return *reinterpret_cast<const s8v*>(T + row * 32 + ((quad ^ ((row >> 1) & 3)) << 3));
}
// swizzled read from unpadded 64-short rows (8 chunks): slot = chunk ^ (row&7)
__device__ __forceinline__ s8v ldsw64(const unsigned short* T, int row, int chunk) {
    return *reinterpret_cast<const s8v*>(T + row * 64 + ((chunk ^ (row & 7)) << 3));
}
// swizzled read from unpadded 128-short rows (16 chunks): XOR within 8-groups
// (rows r and r+8 share a slot -> 2-way aliasing, free on CDNA4)
__device__ __forceinline__ s8v ldsw128(const unsigned short* T, int row, int kc) {
    int sc = (kc & 8) | ((kc & 7) ^ (row & 7));
    return *reinterpret_cast<const s8v*>(T + row * 128 + (sc << 3));
}
__device__ __forceinline__ int detect_f32(const unsigned short* xu) {
    int insane = 0;
    for (int i = 0; i < 128; ++i) {
        unsigned int e = (xu[i] >> 7) & 0xFFu;
        if (e == 255u || (e != 0u && (e < 96u || e > 159u))) ++insane;
    }
    return (insane >= 16) ? 1 : 0;
}

// ------------- fused prep: dtype flag + weight conv + xT transpose ----------
// blocks [0,960): weights (8 el/thread); [960,3008): xT.
// (xqT eliminated: q-GEMM stages straight from xT with a row remap.)
__global__ __launch_bounds__(256)
void prep_kernel(const void* __restrict__ x,
                 const void* __restrict__ w0, const void* __restrict__ w1,
                 const void* __restrict__ w2, const void* __restrict__ w3,
                 const void* __restrict__ w4,
                 unsigned short* __restrict__ wdst,
                 unsigned short* __restrict__ xT,
                 int* __restrict__ dtf)
{
    __shared__ int sflag;
    __shared__ unsigned short T[64][66];
    const int tid = threadIdx.x;
    const int bid = blockIdx.x;
    if (tid == 0) {
        int fl = detect_f32((const unsigned short*)x);
        sflag = fl;
        if (bid == 0) *dtf = fl;
    }
    __syncthreads();
    const bool f = (sflag != 0);

    if (bid < 960) {
        long idx = (long)bid * 2048 + tid * 8;
        const void* s; long off;
        if      (idx <  327680L) { s = w0; off = idx; }
        else if (idx <  393216L) { s = w1; off = idx - 327680L; }
        else if (idx <  917504L) { s = w2; off = idx - 393216L; }
        else if (idx < 1441792L) { s = w3; off = idx - 917504L; }
        else                     { s = w4; off = idx - 1441792L; }
        u16x8 pk;
        if (f) {
            float4 a = *((const float4*)((const float*)s + off));
            float4 b = *((const float4*)((const float*)s + off + 4));
            pk[0]=f2bu(a.x); pk[1]=f2bu(a.y); pk[2]=f2bu(a.z); pk[3]=f2bu(a.w);
            pk[4]=f2bu(b.x); pk[5]=f2bu(b.y); pk[6]=f2bu(b.z); pk[7]=f2bu(b.w);
        } else {
            pk = *((const u16x8*)((const unsigned short*)s + off));
        }
        *reinterpret_cast<u16x8*>(wdst + idx) = pk;
        return;
    }
    // transpose: src x [b][256 c][1024 n] -> xT [b][1024 n][256 c]
    int t = bid - 960;
    int b = t >> 6, r = t & 63;
    int c0 = (r >> 4) * 64, n0 = (r & 15) * 64;
    {
        int nn = tid & 63, cq = tid >> 6;
        long base = ((long)b * 256 + c0 + cq * 16) * 1024 + n0 + nn;
        #pragma unroll
        for (int i = 0; i < 16; ++i)
            T[nn][cq * 16 + i] = f2bu(ldin(x, base + (long)i * 1024, f));
    }
    __syncthreads();
    {
        // vectorized store: lane -> (row group, 4-c chunk); ushort4 per store
        int nnb = tid >> 4;          // 0..15
        int c4  = (tid & 15) << 2;   // 0..60
        #pragma unroll
        for (int i = 0; i < 4; ++i) {
            int nn = nnb + i * 16;
            ushort2 lo = *reinterpret_cast<const ushort2*>(&T[nn][c4]);
            ushort2 hi = *reinterpret_cast<const ushort2*>(&T[nn][c4 + 2]);
            ushort4 pk; pk.x = lo.x; pk.y = lo.y; pk.z = hi.x; pk.w = hi.y;
            *reinterpret_cast<ushort4*>(
                &xT[((long)b * 1024 + n0 + nn) * 256 + c0 + c4]) = pk;
        }
    }
}

// ---------------- MFMA GEMM: C = BN(W @ X), X given transposed --------------
// A [M][K] bf16, B [b][N][K] bf16. Tile BM x 128, K-step = KSTEP (64 or 128).
// Single-buffer staging (dbuf costs residency / regressed -- rounds 4 & 7).
// KSTEP=128 doubles per-step MFMA (32/wave) and halves barrier drains; used
// where the grid caps residency at 2 blocks/CU so the larger LDS is free.
// QSUB: B rows remapped n -> 64*(n>>4)+2*(n&15) (q reads the ::2,::2 spatial
// subset directly from xT; no xqT intermediate).
// OUT_MODE 0: transposed bf16 out0[b][N][M]
// OUT_MODE 1: kv split (out0=kvK [b*8+h][1024 n][32], out1=kvV [b*8+h][128][N])
// OUT_MODE 2: normal external out0 [b'][M][256], b'=n>>8 (N-folded batch)
// OUT_MODE 3: head-split transposed out0 [b*8+h][N][32]  (q projection)
template<int OUT_MODE, bool DO_GELU, bool PRESCALE, int BM, int KSTEP, bool QSUB>
__global__ __launch_bounds__(256)
void mfma_gemm(const unsigned short* __restrict__ A,
               const unsigned short* __restrict__ B,
               const void* __restrict__ gg, const void* __restrict__ bb,
               const void* __restrict__ mmu, const void* __restrict__ vv,
               void* __restrict__ out0, unsigned short* __restrict__ out1,
               int M, int K, int N, const int* __restrict__ dtflag)
{
    constexpr int NF = (BM == 128) ? 4 : 2;
    constexpr int MP0 = BM + 8;  // OUT_MODE 0 epilogue tile stride ([n][m] rows)
    constexpr int MP1 = 136;     // OUT_MODE 1 epilogue tile stride ([m][n] rows)
    constexpr int LOOPSH = (BM + 128) * KSTEP;
    constexpr int TILESH = (OUT_MODE == 1) ? 128 * MP1 : ((OUT_MODE == 0) ? 128 * MP0 : 0);
    constexpr int SMS = (LOOPSH > TILESH) ? LOOPSH : TILESH;
    __shared__ __align__(16) unsigned short smem[SMS];
    __shared__ float sS[BM], sO[BM];
    unsigned short* As = smem;
    unsigned short* Bs = smem + BM * KSTEP;
    unsigned short* Tt = smem;   // epilogue tile aliases As/Bs (dead after K-loop)

    const bool wf = (*dtflag != 0);
    const int tid = threadIdx.x;
    const int lane = tid & 63;
    const int wave = tid >> 6;
    const int quad = lane >> 4;
    const int l15  = lane & 15;
    const int wm2 = (BM == 128) ? (wave >> 1) * 64 : 0;
    const int wn2 = (BM == 128) ? (wave & 1) * 64 : wave * 32;
    const int b  = blockIdx.z;
    const int bm = blockIdx.y * BM;
    const int bn = blockIdx.x * 128;

    if (tid < BM) {
        int m = bm + tid;
        float g  = ldin(gg,  m, wf), be = ldin(bb,  m, wf);
        float mu = ldin(mmu, m, wf), va = ldin(vv,  m, wf);
        float s = g * rsqrtf(va + BN_EPS);
        float o = be - mu * s;
        if (PRESCALE) { s *= 0.17677669529663687f; o *= 0.17677669529663687f; }
        sS[tid] = s; sO[tid] = o;
    }

    const long bstride = QSUB ? 262144L : (long)N * K;
    const unsigned short* Bb = B + (long)b * bstride;

    f4v acc[4][NF];
    #pragma unroll
    for (int i = 0; i < 4; ++i)
        #pragma unroll
        for (int j = 0; j < NF; ++j) acc[i][j] = (f4v){0.f, 0.f, 0.f, 0.f};

    const int lr8 = lane >> 3;   // KSTEP=64: row within 8-row stage group
    const int lc8 = lane & 7;    //           chunk slot 0..7
    const int lr4 = lane >> 4;   // KSTEP=128: row within 4-row stage group
    const int lc16 = lane & 15;  //            chunk slot 0..15

    for (int k0 = 0; k0 < K; k0 += KSTEP) {
        if constexpr (KSTEP == 64) {
            // stage A (BM rows x 64 k, swizzled slot = chunk ^ (row&7))
            #pragma unroll
            for (int j = 0; j < (BM == 128 ? 4 : 2); ++j) {
                int base = wave * (BM == 128 ? 32 : 16) + j * 8;
                int r = base + lr8;
                gld16(A + (long)(bm + r) * K + k0 + ((lc8 ^ (r & 7)) << 3),
                      As + base * 64);
            }
            // stage B (128 rows x 64 k); QSUB remaps the GLOBAL row only
            #pragma unroll
            for (int j = 0; j < 4; ++j) {
                int base = wave * 32 + j * 8;
                int r = base + lr8;
                int n = bn + r;
                int gr = QSUB ? (((n >> 4) << 6) + ((n & 15) << 1)) : n;
                gld16(Bb + (long)gr * K + k0 + ((lc8 ^ (r & 7)) << 3),
                      Bs + base * 64);
            }
        } else {
            // KSTEP=128: rows are 256B; wave-call covers 4 rows x 16 chunks.
            // inverse swizzle on global source: gc = (c&8) | ((c&7)^(r&7))
            #pragma unroll
            for (int j = 0; j < BM / 16; ++j) {
                int base = wave * (BM / 4) + j * 4;
                int r = base + lr4;
                int gc = (lc16 & 8) | ((lc16 & 7) ^ (r & 7));
                gld16(A + (long)(bm + r) * K + k0 + (gc << 3),
                      As + base * 128);
            }
            #pragma unroll
            for (int j = 0; j < 8; ++j) {
                int base = wave * 32 + j * 4;
                int r = base + lr4;
                int gc = (lc16 & 8) | ((lc16 & 7) ^ (r & 7));
                gld16(Bb + (long)(bn + r) * K + k0 + (gc << 3),
                      Bs + base * 128);
            }
        }
        __syncthreads();

        #pragma unroll
        for (int sk = 0; sk < KSTEP / 32; ++sk) {
            const int kc = sk * 4 + quad;
            s8v af[4], bfr[NF];
            #pragma unroll
            for (int i = 0; i < 4; ++i)
                af[i] = (KSTEP == 64) ? ldsw64(As, wm2 + i * 16 + l15, kc)
                                      : ldsw128(As, wm2 + i * 16 + l15, kc);
            #pragma unroll
            for (int j = 0; j < NF; ++j)
                bfr[j] = (KSTEP == 64) ? ldsw64(Bs, wn2 + j * 16 + l15, kc)
                                       : ldsw128(Bs, wn2 + j * 16 + l15, kc);
            #pragma unroll
            for (int i = 0; i < 4; ++i)
                #pragma unroll
                for (int j = 0; j < NF; ++j)
                    acc[i][j] = __builtin_amdgcn_mfma_f32_16x16x32_bf16(
                        af[i], bfr[j], acc[i][j], 0, 0, 0);
        }
        __syncthreads();
    }

    // ---------------- epilogue: BN(+GELU) then store ----------------
    #pragma unroll
    for (int i = 0; i < 4; ++i) {
        int m0l = wm2 + i * 16 + quad * 4;
        int m0  = bm + m0l;
        float s0 = sS[m0l + 0], o0 = sO[m0l + 0];
        float s1 = sS[m0l + 1], o1 = sO[m0l + 1];
        float s2 = sS[m0l + 2], o2 = sO[m0l + 2];
        float s3 = sS[m0l + 3], o3 = sO[m0l + 3];
        #pragma unroll
        for (int j = 0; j < NF; ++j) {
            int nl = wn2 + j * 16 + l15;
            int n = bn + nl;
            float v0 = acc[i][j][0] * s0 + o0;
            float v1 = acc[i][j][1] * s1 + o1;
            float v2 = acc[i][j][2] * s2 + o2;
            float v3 = acc[i][j][3] * s3 + o3;
            if (DO_GELU) {
                v0 = gelu_exact(v0); v1 = gelu_exact(v1);
                v2 = gelu_exact(v2); v3 = gelu_exact(v3);
            }
            if (OUT_MODE == 0) {
                // stage [n][m] tile; coalesced read-out below
                ushort4 pk; pk.x = f2bu(v0); pk.y = f2bu(v1);
                pk.z = f2bu(v2); pk.w = f2bu(v3);
                *reinterpret_cast<ushort4*>(&Tt[nl * MP0 + m0l]) = pk;
            } else if (OUT_MODE == 1) {
                int h = m0 / 160, seg = m0 - h * 160;
                if (seg < 32) {
                    ushort4 pk; pk.x = f2bu(v0); pk.y = f2bu(v1);
                    pk.z = f2bu(v2); pk.w = f2bu(v3);
                    *reinterpret_cast<ushort4*>(
                        (unsigned short*)out0 + ((long)(b * 8 + h) * 1024 + n) * 32 + seg) = pk;
                } else {
                    // stage V rows [m][n]; coalesced read-out below
                    Tt[(m0l + 0) * MP1 + nl] = f2bu(v0);
                    Tt[(m0l + 1) * MP1 + nl] = f2bu(v1);
                    Tt[(m0l + 2) * MP1 + nl] = f2bu(v2);
                    Tt[(m0l + 3) * MP1 + nl] = f2bu(v3);
                }
            } else if (OUT_MODE == 2) {
                int b2 = n >> 8, nl2 = n & 255;
                long ob = ((long)b2 * M + m0) * 256 + nl2;
                if (wf) {
                    ((float*)out0)[ob + 0L * 256] = v0;
                    ((float*)out0)[ob + 1L * 256] = v1;
                    ((float*)out0)[ob + 2L * 256] = v2;
                    ((float*)out0)[ob + 3L * 256] = v3;
                } else {
                    ((unsigned short*)out0)[ob + 0L * 256] = f2bu(v0);
                    ((unsigned short*)out0)[ob + 1L * 256] = f2bu(v1);
                    ((unsigned short*)out0)[ob + 2L * 256] = f2bu(v2);
                    ((unsigned short*)out0)[ob + 3L * 256] = f2bu(v3);
                }
            } else {  // OUT_MODE == 3
                int h = m0 >> 5;
                ushort4 pk; pk.x = f2bu(v0); pk.y = f2bu(v1);
                pk.z = f2bu(v2); pk.w = f2bu(v3);
                *reinterpret_cast<ushort4*>(
                    (unsigned short*)out0 + ((long)(b * 8 + h) * 256 + n) * 32 + (m0 & 31)) = pk;
            }
        }
    }

    if (OUT_MODE == 0) {
        __syncthreads();
        // write 128 n-rows of BM m each, ushort8 per lane (fully coalesced)
        constexpr int CPR = BM / 8;              // 16B-chunks per n-row
        long ob = ((long)b * N + bn) * M + bm;
        #pragma unroll
        for (int c = 0; c < BM / 16; ++c) {      // 128*CPR/256 iters
            int cc = c * 256 + tid;
            int n = cc / CPR, mc = (cc % CPR) << 3;
            *reinterpret_cast<u16x8*>((unsigned short*)out0 + ob + (long)n * M + mc) =
                *reinterpret_cast<const u16x8*>(&Tt[n * MP0 + mc]);
        }
    } else if (OUT_MODE == 1) {
        __syncthreads();
        // V rows of this tile: all local m except the (single, aligned) K window
        int h0 = (bm + 159) / 160;
        int ks = h0 * 160;                      // K window [ks, ks+32) if in tile
        bool hasK = (ks < bm + 128);
        int kl = hasK ? (ks - bm) : 128;        // local K window start
        int nrows = hasK ? 96 : 128;
        for (int c = tid; c < nrows * 16; c += 256) {
            int row = c >> 4, ch = (c & 15) << 3;
            int ml = (row < kl) ? row : (row + 32);
            int m = bm + ml;
            int hh = m / 160, seg = m - hh * 160;
            *reinterpret_cast<u16x8*>(out1 +
                (((long)(b * 8 + hh) * 128) + (seg - 32)) * (long)N + bn + ch) =
                *reinterpret_cast<const u16x8*>(&Tt[ml * MP1 + ch]);
        }
    }
}

// ------- MFMA flash attention + GELU, static-max softmax, deferred sum ------
// Scores are BN-normalized (std ~0.5, max ~3): exp(min(s,30)) never overflows,
// so no online max, no alpha rescale, no per-tile reductions.
// K-loop: double-buffered K/V tiles, stage(t+1) issued BEFORE compute(t),
// single __syncthreads per tile (T3 minimum-2-phase; overlap = full compute).
// kvK [b*8+h][1024 n][32 d], kvV [b*8+h][128 v][1024 n],
// qh  [b*8+h][256 q][32 d] (pre-scaled), goT [b][256 q][1024 (h,v)]
__global__ __launch_bounds__(512, 4)
void attn_mfma(const unsigned short* __restrict__ kvK,
               const unsigned short* __restrict__ kvV,
               const unsigned short* __restrict__ qh,
               unsigned short* __restrict__ goT)
{
    __shared__ unsigned short Ks[2][64 * 32];   // 8 KB,  xor-swizzled
    __shared__ unsigned short Vs[2][128 * 64];  // 32 KB, xor-swizzled
    __shared__ unsigned short Ps[128][72];      // 18.4 KB
    __shared__ float redS[128];

    const int tid = threadIdx.x;
    const int lane = tid & 63;
    const int wave = tid >> 6;     // 0..7
    const int quad = lane >> 4;
    const int l15  = lane & 15;
    const int h    = blockIdx.x;   // 0..7
    const int b    = blockIdx.y;   // 0..31
    const int q0   = blockIdx.z * 128;   // q-half (z so siblings share XCD)
    const int wq   = wave * 16;          // block-local q base for this wave

    const unsigned short* Qb = qh  + (long)(b * 8 + h) * 256 * 32;
    const unsigned short* Kb = kvK + (long)(b * 8 + h) * 1024 * 32;
    const unsigned short* Vb = kvV + (long)(b * 8 + h) * 128 * 1024;

    s8v qf = ldfrag(Qb + (long)(q0 + wq + l15) * 32 + quad * 8);

    // hoisted per-lane global source pointers (tile t adds t*64 n-columns)
    const unsigned short* pK = Kb;
    if (wave < 4) {
        int r = wave * 16 + (lane >> 2);
        int c = (lane & 3) ^ ((r >> 1) & 3);
        pK = Kb + (long)r * 32 + (c << 3);
    }
    const int rb = wave * 16;
    const int r0 = rb + (lane >> 3), r1 = r0 + 8;
    const int sl = lane & 7;
    const unsigned short* pV0 = Vb + (long)r0 * 1024 + ((sl ^ (r0 & 7)) << 3);
    const unsigned short* pV1 = Vb + (long)r1 * 1024 + ((sl ^ (r1 & 7)) << 3);

    f4v o[8];
    #pragma unroll
    for (int i = 0; i < 8; ++i) o[i] = (f4v){0.f, 0.f, 0.f, 0.f};
    float rs[4] = {0.f, 0.f, 0.f, 0.f};   // deferred row-sum partials

    // prologue: stage tile 0 into buffer 0
    if (wave < 4) gld16(pK, &Ks[0][wave * 16 * 32]);
    gld16(pV0, &Vs[0][rb * 64]);
    gld16(pV1, &Vs[0][(rb + 8) * 64]);
    __syncthreads();               // drain stage(0)

    for (int t = 0; t < 16; ++t) {
        const int cur = t & 1;
        if (t < 15) {              // issue stage(t+1) BEFORE compute(t)
            const int nxt = cur ^ 1;
            const long adv = (long)(t + 1) * 64;
            if (wave < 4) gld16(pK + adv * 32, &Ks[nxt][wave * 16 * 32]);
            gld16(pV0 + adv, &Vs[nxt][rb * 64]);
            gld16(pV1 + adv, &Vs[nxt][(rb + 8) * 64]);
        }

        // S = Q K^T (16 q x 64 n per wave), then p = exp(s) straight away
        #pragma unroll
        for (int j = 0; j < 4; ++j) {
            s8v kf = ldsw32(&Ks[cur][0], j * 16 + l15, quad);
            f4v z = (f4v){0.f, 0.f, 0.f, 0.f};
            f4v sa = __builtin_amdgcn_mfma_f32_16x16x32_bf16(qf, kf, z, 0, 0, 0);
            #pragma unroll
            for (int r = 0; r < 4; ++r) {
                float p = __expf(fminf(sa[r], 30.f));
                rs[r] += p;
                Ps[wq + quad * 4 + r][j * 16 + l15] = f2bu(p);
            }
        }
        // wave-private P rows: LDS ops in-order per wave -> no barrier
        // O += V P^T
        #pragma unroll
        for (int ks = 0; ks < 2; ++ks) {
            s8v pf = ldfrag(&Ps[wq + l15][ks * 32 + quad * 8]);
            #pragma unroll
            for (int i = 0; i < 8; ++i) {
                s8v vf = ldsw64(&Vs[cur][0], i * 16 + l15, ks * 4 + quad);
                o[i] = __builtin_amdgcn_mfma_f32_16x16x32_bf16(vf, pf, o[i], 0, 0, 0);
            }
        }
        // single barrier per tile: drains stage(t+1) (vmcnt(0)) and orders
        // this tile's LDS reads before buffer[cur] is overwritten at t+1
        __syncthreads();
    }

    // single end-of-kernel row-sum reduction (16-lane groups)
    #pragma unroll
    for (int r = 0; r < 4; ++r) {
        float s = rs[r];
        s += __shfl_xor(s, 1);
        s += __shfl_xor(s, 2);
        s += __shfl_xor(s, 4);
        s += __shfl_xor(s, 8);
        if (l15 == 0) redS[wq + quad * 4 + r] = s;
    }
    float linv = 1.0f / redS[wq + l15];
    int q = q0 + wq + l15;
    #pragma unroll
    for (int i = 0; i < 8; ++i) {
        ushort4 pk;
        pk.x = f2bu(gelu_exact(o[i][0] * linv));
        pk.y = f2bu(gelu_exact(o[i][1] * linv));
        pk.z = f2bu(gelu_exact(o[i][2] * linv));
        pk.w = f2bu(gelu_exact(o[i][3] * linv));
        *reinterpret_cast<ushort4*>(
            goT + ((long)b * 256 + q) * 1024 + h * 128 + i * 16 + quad * 4) = pk;
    }
}

// ---------------------------------------------------------------------------
extern "C" void kernel_launch(void* const* d_in, const int* in_sizes, int n_in,
                              void* d_out, int out_size, void* d_ws, size_t ws_size,
                              hipStream_t stream)
{
    const void* x     = d_in[0];
    const void* kv_w  = d_in[1];
    const void* kv_g  = d_in[2];  const void* kv_b  = d_in[3];
    const void* kv_m  = d_in[4];  const void* kv_v  = d_in[5];
    const void* q_w   = d_in[6];
    const void* q_g   = d_in[7];  const void* q_b   = d_in[8];
    const void* q_m   = d_in[9];  const void* q_v   = d_in[10];
    const void* mg_w  = d_in[11];
    const void* mg_g  = d_in[12]; const void* mg_b  = d_in[13];
    const void* mg_m  = d_in[14]; const void* mg_v  = d_in[15];
    const void* fc1_w = d_in[16];
    const void* bn1_g = d_in[17]; const void* bn1_b = d_in[18];
    const void* bn1_m = d_in[19]; const void* bn1_v = d_in[20];
    const void* fc2_w = d_in[21];
    const void* bn2_g = d_in[22]; const void* bn2_b = d_in[23];
    const void* bn2_m = d_in[24]; const void* bn2_v = d_in[25];

    // ws layout (bf16 elements)
    unsigned short* ws  = (unsigned short*)d_ws;
    int*            dtf = (int*)d_ws;
    unsigned short* wsW  = ws + 8;               // 1,966,080
    unsigned short* wKV  = wsW;
    unsigned short* wQ   = wsW + 327680L;
    unsigned short* wMG  = wsW + 393216L;
    unsigned short* wFC1 = wsW + 917504L;
    unsigned short* wFC2 = wsW + 1441792L;
    unsigned short* xT   = ws + 1966088L;        // 8,388,608 (aliased by goT)
    unsigned short* goT  = xT;
    unsigned short* qhb  = ws + 12451848L;       // 2,097,152
    unsigned short* kvK  = ws + 14549000L;       // 8,388,608
    unsigned short* kvV  = ws + 22937608L;       // 33,554,432 (aliased by y1/y2)
    unsigned short* y1T  = kvV;                  // [8192][512]
    unsigned short* y2T  = kvV + 4194304L;       // [8192][1024]

    dim3 blk(256, 1, 1);

    // fused prep: dtype detect + weight conv + xT (no xqT)
    prep_kernel<<<3008, blk, 0, stream>>>(
        x, kv_w, q_w, mg_w, fc1_w, fc2_w, wsW, xT, dtf);

    // q proj + BN (scale folded) -> qh [b*8+h][256][32]
    // B = xT with QSUB row remap (::2,::2 spatial subset)
    mfma_gemm<3, false, true, 64, 64, true><<<dim3(2, 4, 32), blk, 0, stream>>>(
        wQ, xT, q_g, q_b, q_m, q_v, qhb, nullptr, 256, 256, 256, dtf);

    // kv proj + BN, split K [b*8+h][1024][32] / V [b*8+h][128][1024]
    mfma_gemm<1, false, false, 128, 64, false><<<dim3(8, 10, 32), blk, 0, stream>>>(
        wKV, xT, kv_g, kv_b, kv_m, kv_v, kvK, kvV, 1280, 256, 1024, dtf);

    // flash attention + GELU -> goT [b][256][1024]
    attn_mfma<<<dim3(8, 32, 2), dim3(512, 1, 1), 0, stream>>>(kvK, kvV, qhb, goT);

    // merge proj + BN -> y1T [8192][512]  (BM=64, KSTEP=128: 32 MFMA/wave/step)
    mfma_gemm<0, false, false, 64, 128, false><<<dim3(64, 8, 1), blk, 0, stream>>>(
        wMG, goT, mg_g, mg_b, mg_m, mg_v, y1T, nullptr, 512, 1024, 8192, dtf);

    // fc1 + BN + GELU -> y2T [8192][1024]  (BM=128: kv structure)
    mfma_gemm<0, true, false, 128, 64, false><<<dim3(64, 8, 1), blk, 0, stream>>>(
        wFC1, y1T, bn1_g, bn1_b, bn1_m, bn1_v, y2T, nullptr, 1024, 512, 8192, dtf);

    // fc2 + BN -> d_out [b][512][16][16]  (BM=64, KSTEP=128)
    mfma_gemm<2, false, false, 64, 128, false><<<dim3(64, 8, 1), blk, 0, stream>>>(
        wFC2, y2T, bn2_g, bn2_b, bn2_m, bn2_v, d_out, nullptr, 512, 1024, 8192, dtf);
}